// Round 16
// baseline (1189.466 us; speedup 1.0000x reference)
//
#include <hip/hip_runtime.h>
#include <hip/hip_bf16.h>
#include <stdint.h>

#define S_LEN 256
#define BATCH 64
#define HD 256
#define NT 9
#define NTOK (S_LEN*BATCH)   // 16384

typedef _Float16 hf2 __attribute__((ext_vector_type(2)));
typedef short bf16x8 __attribute__((ext_vector_type(8)));
typedef float f32x4 __attribute__((ext_vector_type(4)));
typedef int i32x4 __attribute__((ext_vector_type(4)));
typedef uint32_t u32x4 __attribute__((ext_vector_type(4)));

__device__ __forceinline__ float sigf(float x){ return 1.f/(1.f+__expf(-x)); }
__device__ __forceinline__ float tanh_(float x){ return 1.f - 2.f/(__expf(2.f*x)+1.f); }
__device__ __forceinline__ float wredsum(float v){
#pragma unroll
  for (int s = 32; s > 0; s >>= 1) v += __shfl_xor(v, s);
  return v;
}
__device__ __forceinline__ uint16_t f2b(float f){
  __hip_bfloat16 h = __float2bfloat16(f);
  return *(uint16_t*)&h;
}
__device__ __forceinline__ float b2f(uint16_t u){
  union{uint32_t i; float f;} a; a.i = ((uint32_t)u)<<16; return a.f;
}

// ---- merged prep: wih16/bias + gathered bf16 emb + per-column amax scale ----
__global__ __launch_bounds__(256) void prep_all(const int* __restrict__ inp,
    const float* __restrict__ emb,
    const float* __restrict__ wihf, const float* __restrict__ wihb,
    const float* __restrict__ bif, const float* __restrict__ bhf,
    const float* __restrict__ bib, const float* __restrict__ bhb,
    const float* __restrict__ whf, const float* __restrict__ whb,
    uint16_t* __restrict__ wih16, float* __restrict__ bias,
    uint16_t* __restrict__ gemb, float* __restrict__ mult){
  int blk = blockIdx.x, t = threadIdx.x;
  int idx = blk*256 + t;        // < 524288
  {
    int n = idx >> 8, k = idx & 255;
    const float* w = (n < 1024) ? wihf : wihb;
    wih16[idx] = f2b(w[(n & 1023)*256 + k]);
    if (idx < 2048)
      bias[idx] = (idx < 1024) ? (bif[idx] + bhf[idx]) : (bib[idx-1024] + bhb[idx-1024]);
  }
  {
    int m = idx >> 5;
    int k8 = (idx & 31)*8;
    int tok = inp[(m & 63)*S_LEN + (m >> 6)];
    const float* src = emb + (size_t)tok*256 + k8;
    float4 v0 = *(const float4*)(src);
    float4 v1 = *(const float4*)(src+4);
    uint16_t t16[8];
    t16[0]=f2b(v0.x); t16[1]=f2b(v0.y); t16[2]=f2b(v0.z); t16[3]=f2b(v0.w);
    t16[4]=f2b(v1.x); t16[5]=f2b(v1.y); t16[6]=f2b(v1.z); t16[7]=f2b(v1.w);
    *(uint4*)&gemb[(size_t)m*256 + k8] = *(uint4*)t16;
  }
  if (t < 64) {
    int dir = blk >> 10, col = blk & 1023;
    const float* w = (dir ? whb : whf) + (size_t)col*256 + t*4;
    float4 v = *(const float4*)w;
    float amax = fmaxf(fmaxf(fabsf(v.x), fabsf(v.y)), fmaxf(fabsf(v.z), fabsf(v.w)));
#pragma unroll
    for (int s = 32; s > 0; s >>= 1) amax = fmaxf(amax, __shfl_xor(amax, s));
    if (t == 0) mult[blk] = amax / 16129.f;
  }
}

// ---- pack w_hh to i8 A-fragments for lstm13 ----
// Flat dword idx = dir*65536 + tid*64 + r*4 + d; r = nt*4+kc.
// Lane (l=tid&63) A-frag row n = w*64 + nt*16 + (l&15) (w = tid>>6);
// k = kc*64 + (l>>4)*16 + d*4 + e.  n gate-minor: gate=n&3, unit=n>>2;
// source row = gate*256+unit of w_hh_dir; col-scale mult[dir*1024+gate*256+unit].
__global__ void prep_pack11(const float* __restrict__ whf, const float* __restrict__ whb,
                            const float* __restrict__ mult, uint32_t* __restrict__ wpk){
  int idx = blockIdx.x*256 + threadIdx.x;   // < 131072
  int d = idx & 3;
  int r = (idx >> 2) & 15;
  int tid = (idx >> 6) & 1023;
  int dir = idx >> 16;
  int w = tid >> 6, l = tid & 63;
  int nt = r >> 2, kc = r & 3;
  int n = w*64 + nt*16 + (l & 15);
  int gate = n & 3, unit = n >> 2;
  int col = gate*256 + unit;
  int kbase = kc*64 + (l >> 4)*16 + d*4;
  const float* wsrc = (dir ? whb : whf) + (size_t)col*256 + kbase;
  float sw = mult[dir*1024 + col] * 127.f;
  float inv = (sw > 0.f) ? (1.f/sw) : 0.f;
  uint32_t pk = 0;
#pragma unroll
  for (int e = 0; e < 4; ++e) {
    float q = rintf(wsrc[e] * inv);
    q = fminf(127.f, fmaxf(-127.f, q));
    int qi = (int)q;
    pk |= ((uint32_t)(qi & 0xff)) << (8*e);
  }
  wpk[idx] = pk;
}

// ---- input projection via MFMA, 128x128 tile; bn-fast grid + XCD-chunk swizzle ----
__global__ __launch_bounds__(256, 2) void inproj_mfma3(const uint16_t* __restrict__ gemb,
    const uint16_t* __restrict__ wih16, const float* __restrict__ bias,
    uint16_t* __restrict__ xgf, uint16_t* __restrict__ xgb){
  __shared__ uint16_t As[128][72];
  __shared__ uint16_t Bs[128][72];
  int flat = blockIdx.x + blockIdx.y*16;   // 2048 blocks
  int nf = (flat & 7)*256 + (flat >> 3);
  int bn = nf & 15, bm = nf >> 4;
  int tid = threadIdx.x;
  int w = tid >> 6, l = tid & 63;
  int lr = l & 15, lg = l >> 4;
  f32x4 acc[2][8];
#pragma unroll
  for (int am = 0; am < 2; ++am)
#pragma unroll
    for (int cf = 0; cf < 8; ++cf) acc[am][cf] = (f32x4){0.f,0.f,0.f,0.f};

  int sr = tid >> 1, sh = tid & 1;

  for (int k0 = 0; k0 < 256; k0 += 64) {
    {
      const uint16_t* asrc = gemb + (size_t)(bm*128 + sr)*256 + k0 + sh*32;
      uint4 a0 = *(const uint4*)(asrc+0);
      uint4 a1 = *(const uint4*)(asrc+8);
      uint4 a2 = *(const uint4*)(asrc+16);
      uint4 a3 = *(const uint4*)(asrc+24);
      *(uint4*)&As[sr][sh*32+0]  = a0;
      *(uint4*)&As[sr][sh*32+8]  = a1;
      *(uint4*)&As[sr][sh*32+16] = a2;
      *(uint4*)&As[sr][sh*32+24] = a3;
    }
    {
      const uint16_t* bsrc = wih16 + (size_t)(bn*128 + sr)*256 + k0 + sh*32;
      uint4 b0 = *(const uint4*)(bsrc+0);
      uint4 b1 = *(const uint4*)(bsrc+8);
      uint4 b2 = *(const uint4*)(bsrc+16);
      uint4 b3 = *(const uint4*)(bsrc+24);
      *(uint4*)&Bs[sr][sh*32+0]  = b0;
      *(uint4*)&Bs[sr][sh*32+8]  = b1;
      *(uint4*)&Bs[sr][sh*32+16] = b2;
      *(uint4*)&Bs[sr][sh*32+24] = b3;
    }
    __syncthreads();
#pragma unroll
    for (int ks = 0; ks < 2; ++ks) {
      int koff = ks*32 + lg*8;
      bf16x8 a0 = *(const bf16x8*)&As[32*w + lr][koff];
      bf16x8 a1 = *(const bf16x8*)&As[32*w + 16 + lr][koff];
#pragma unroll
      for (int cf = 0; cf < 8; ++cf) {
        bf16x8 b = *(const bf16x8*)&Bs[cf*16 + lr][koff];
        acc[0][cf] = __builtin_amdgcn_mfma_f32_16x16x32_bf16(a0, b, acc[0][cf], 0, 0, 0);
        acc[1][cf] = __builtin_amdgcn_mfma_f32_16x16x32_bf16(a1, b, acc[1][cf], 0, 0, 0);
      }
    }
    __syncthreads();
  }
  int n0 = bn*128;
  bool back = (n0 >= 1024);
  uint16_t* dst = back ? xgb : xgf;
  int nb0 = back ? (n0 - 1024) : n0;
#pragma unroll
  for (int cf = 0; cf < 8; ++cf) {
    int nc = cf*16 + lr;
    int nd = nb0 + nc;
    int gj = (nd & 255)*4 + (nd >> 8); // unit-major, gate-minor position
    float bv = bias[n0 + nc];
#pragma unroll
    for (int am = 0; am < 2; ++am)
#pragma unroll
    for (int r = 0; r < 4; ++r) {
      int mix = bm*128 + 32*w + am*16 + lg*4 + r;
      dst[(size_t)mix*1024 + gj] = f2b(acc[am][cf][r] + bv);
    }
  }
}

// ---- recurrence via MFMA: 8 wgs = (dir x 4 chain-groups of 16); 1024 threads ----
// Per step: z^T = W(i8) . h^T(i8) with v_mfma_i32_16x16x64_i8 (inline asm).
// Gate-minor n => lane's 4 C-regs = the 4 gates of (chain m=l&15, unit) -- no
// cross-lane exchange. W: 64 pinned VGPR dwords. h: LDS [kchunk][m][16B] dbuf,
// B-read = consecutive-16B ds_read_b128 (conflict-free). Raw barrier, lgkm-only.
__global__ __launch_bounds__(1024, 4)
void lstm13(const uint32_t* __restrict__ wpk, const float* __restrict__ mult,
    const uint16_t* __restrict__ xgf, const uint16_t* __restrict__ xgb,
    __hip_bfloat16* __restrict__ hout){
  int wg = blockIdx.x;           // 0..7
  int dir = wg >> 2;
  int cb = (wg & 3) * 16;        // chain base
  int tid = threadIdx.x;
  int l = tid & 63, w = tid >> 6;
  int m = l & 15, rg = l >> 4;
  __shared__ __align__(16) unsigned char hsb[8192];   // h i8, [buf][kchunk][m][16B]

  // W fragments: 16 x u32x4 (nt*4+kc), per-thread contiguous in wpk
  const u32x4* wp4 = (const u32x4*)wpk + (size_t)(dir*1024 + tid)*16;
  u32x4 wfrag[16];
#pragma unroll
  for (int r = 0; r < 16; ++r) wfrag[r] = wp4[r];
#pragma unroll
  for (int r = 0; r < 16; ++r) asm volatile("" : "+v"(wfrag[r]));
  asm volatile("" ::: "memory");

  int unitv[4];
  uint32_t mmlo[4], mmhi[4];
#pragma unroll
  for (int nt = 0; nt < 4; ++nt) {
    int unit = w*16 + nt*4 + rg;
    unitv[nt] = unit;
    const float* mp = mult + dir*1024 + unit;
    mmlo[nt] = (uint32_t)f2b(mp[0])   | ((uint32_t)f2b(mp[256]) << 16);
    mmhi[nt] = (uint32_t)f2b(mp[512]) | ((uint32_t)f2b(mp[768]) << 16);
  }

  uint32_t* hs32 = (uint32_t*)hsb;
  hs32[tid] = 0u;
  hs32[tid + 1024] = 0u;
  float cst[4] = {0.f, 0.f, 0.f, 0.f};
  const uint16_t* xbase = (dir ? xgb : xgf) + (size_t)(cb + m)*1024;
  __syncthreads();

  for (int t = 0; t < S_LEN; ++t) {
    int ts = dir ? (S_LEN-1-t) : t;
    int cur = t & 1;
    const uint16_t* xp = xbase + (size_t)ts*65536;
    // x for this lane's 4 (m,unit) outputs -- issued early, consumed after MFMA
    uint2 xq[4];
#pragma unroll
    for (int nt = 0; nt < 4; ++nt) xq[nt] = *(const uint2*)(xp + unitv[nt]*4);

    i32x4 acc[4];
#pragma unroll
    for (int nt = 0; nt < 4; ++nt) acc[nt] = (i32x4){0,0,0,0};
    const unsigned char* rb = hsb + cur*4096;
#pragma unroll
    for (int kc = 0; kc < 4; ++kc) {
      u32x4 bq = *(const u32x4*)(rb + (kc*4 + rg)*256 + m*16);
#pragma unroll
      for (int nt = 0; nt < 4; ++nt) {
        asm volatile("v_mfma_i32_16x16x64_i8 %0, %1, %2, %0"
                     : "+v"(acc[nt]) : "v"(wfrag[nt*4 + kc]), "v"(bq));
      }
    }
    asm volatile("s_nop 7\n\ts_nop 7" ::: );   // MFMA->VALU hazard guard
    unsigned char* wb = hsb + (cur^1)*4096;
#pragma unroll
    for (int nt = 0; nt < 4; ++nt) {
      float mg0 = b2f((uint16_t)(mmlo[nt] & 0xffff));
      float mg1 = b2f((uint16_t)(mmlo[nt] >> 16));
      float mg2 = b2f((uint16_t)(mmhi[nt] & 0xffff));
      float mg3 = b2f((uint16_t)(mmhi[nt] >> 16));
      float zi = (float)acc[nt][0]*mg0 + b2f((uint16_t)(xq[nt].x & 0xffff));
      float zf = (float)acc[nt][1]*mg1 + b2f((uint16_t)(xq[nt].x >> 16));
      float zg = (float)acc[nt][2]*mg2 + b2f((uint16_t)(xq[nt].y & 0xffff));
      float zo = (float)acc[nt][3]*mg3 + b2f((uint16_t)(xq[nt].y >> 16));
      float ig = sigf(zi), fg = sigf(zf), gg = tanh_(zg), og = sigf(zo);
      cst[nt] = fg*cst[nt] + ig*gg;
      float h = og * tanh_(cst[nt]);
      int q = (int)rintf(h * 127.f);
      wb[w*256 + m*16 + nt*4 + rg] = (unsigned char)(q & 0xff);
      hout[((size_t)ts*BATCH + cb + m)*512 + dir*256 + unitv[nt]] = __float2bfloat16(h);
    }
    // raw barrier: drain LDS only; global loads/stores stay in flight
    __builtin_amdgcn_sched_barrier(0);
    asm volatile("s_waitcnt lgkmcnt(0)" ::: "memory");
    __builtin_amdgcn_sched_barrier(0);
    __builtin_amdgcn_s_barrier();
    __builtin_amdgcn_sched_barrier(0);
  }
}

// ---- output projection: 1024 blocks x 16 tokens (amortize w_out staging) ----
__global__ __launch_bounds__(256) void outproj2(const __hip_bfloat16* __restrict__ hb,
    const float* __restrict__ w_out, const float* __restrict__ b_out,
    float* __restrict__ em){
  __shared__ float wsm[NT*512];
  __shared__ float bsm[NT];
  int tid = threadIdx.x;
  for (int i = tid; i < NT*512; i += 256) wsm[i] = w_out[512 + i];  // rows 1..9
  if (tid < NT) bsm[tid] = b_out[1 + tid];
  __syncthreads();
  int wave = tid >> 6, l = tid & 63;
#pragma unroll
  for (int it = 0; it < 4; ++it) {
    int m = blockIdx.x*16 + it*4 + wave;
    const __hip_bfloat16* hp = hb + (size_t)m*512;
    float hv[8];
#pragma unroll
    for (int q = 0; q < 8; ++q) hv[q] = __bfloat162float(hp[l + 64*q]);
    for (int jj = 0; jj < NT; ++jj) {
      float p = 0.f;
#pragma unroll
      for (int q = 0; q < 8; ++q) p += hv[q]*wsm[jj*512 + 64*q + l];
      p = wredsum(p);
      if (l == 0) em[(size_t)m*NT + jj] = p + bsm[jj];
    }
  }
}

// ---- CRF: one wave per batch item; lanes 0..8 hold the 9-state score ----
__global__ __launch_bounds__(64) void crf(const int* __restrict__ tags,
    const float* __restrict__ em, const float* __restrict__ start_t,
    const float* __restrict__ end_t, const float* __restrict__ trans,
    float* __restrict__ part){
  int b = blockIdx.x;
  int l = threadIdx.x;
  float np = 0.f;
  for (int t = l; t < S_LEN; t += 64) {
    int tg = tags[b*S_LEN + t] - 1;
    float e = em[(size_t)(t*BATCH + b)*NT + tg];
    float tr = (t == 0) ? start_t[tg] : trans[(tags[b*S_LEN + t - 1] - 1)*NT + tg];
    np += e + tr;
  }
  float num = wredsum(np);
  num += end_t[tags[b*S_LEN + S_LEN-1] - 1];
  int j = (l < NT) ? l : 0;
  float tj[NT];
#pragma unroll
  for (int i = 0; i < NT; ++i) tj[i] = trans[i*NT + j];
  float sc = start_t[j] + em[(size_t)b*NT + j];
  for (int t = 1; t < S_LEN; ++t) {
    float e = em[(size_t)(t*BATCH + b)*NT + j];
    float m = -1e30f;
    float vals[NT];
#pragma unroll
    for (int i = 0; i < NT; ++i) { float si = __shfl(sc, i); vals[i] = si + tj[i]; m = fmaxf(m, vals[i]); }
    float ssum = 0.f;
#pragma unroll
    for (int i = 0; i < NT; ++i) ssum += __expf(vals[i] - m);
    sc = e + m + __logf(ssum);
  }
  float vj = (l < NT) ? (sc + end_t[l]) : -1e30f;
  float mx = vj;
#pragma unroll
  for (int s2 = 32; s2 > 0; s2 >>= 1) mx = fmaxf(mx, __shfl_xor(mx, s2));
  float es = __expf(vj - mx);
  es = wredsum(es);
  if (l == 0) part[b] = num - (mx + __logf(es));
}

__global__ void finalize(const float* __restrict__ part, float* __restrict__ out){
  float v = part[threadIdx.x];
  v = wredsum(v);
  if (threadIdx.x == 0) out[0] = -(v / 64.f);
}

extern "C" void kernel_launch(void* const* d_in, const int* in_sizes, int n_in,
                              void* d_out, int out_size, void* d_ws, size_t ws_size,
                              hipStream_t stream) {
  (void)in_sizes; (void)n_in; (void)out_size; (void)ws_size;
  const int*   inputs  = (const int*)d_in[0];
  const int*   tags    = (const int*)d_in[1];
  const float* emb     = (const float*)d_in[3];
  const float* w_ih_f  = (const float*)d_in[4];
  const float* w_hh_f  = (const float*)d_in[5];
  const float* b_ih_f  = (const float*)d_in[6];
  const float* b_hh_f  = (const float*)d_in[7];
  const float* w_ih_b  = (const float*)d_in[8];
  const float* w_hh_b  = (const float*)d_in[9];
  const float* b_ih_b  = (const float*)d_in[10];
  const float* b_hh_b  = (const float*)d_in[11];
  const float* w_out   = (const float*)d_in[12];
  const float* b_out   = (const float*)d_in[13];
  const float* start_t = (const float*)d_in[14];
  const float* end_t   = (const float*)d_in[15];
  const float* trans   = (const float*)d_in[16];

  char* ws = (char*)d_ws;
  size_t off = 0;
  auto alloc = [&](size_t bytes) -> void* {
    void* p = ws + off;
    off = (off + bytes + 255) & ~(size_t)255;
    return p;
  };
  uint16_t* xgf = (uint16_t*)alloc((size_t)NTOK*1024*2);
  uint16_t* xgb = (uint16_t*)alloc((size_t)NTOK*1024*2);
  __hip_bfloat16* hbf = (__hip_bfloat16*)alloc((size_t)NTOK*512*2);
  float*    em    = (float*)alloc((size_t)NTOK*NT*4);
  uint16_t* wih16 = (uint16_t*)alloc((size_t)2048*256*2);
  uint16_t* gemb  = (uint16_t*)alloc((size_t)NTOK*256*2);
  float*    bias  = (float*)alloc((size_t)2048*4);
  float*    mult  = (float*)alloc((size_t)2048*4);
  uint32_t* wpk   = (uint32_t*)alloc((size_t)2*65536*4);
  float*    part  = (float*)alloc((size_t)64*4);

  prep_all<<<2048, 256, 0, stream>>>(inputs, emb, w_ih_f, w_ih_b, b_ih_f, b_hh_f,
                                     b_ih_b, b_hh_b, w_hh_f, w_hh_b,
                                     wih16, bias, gemb, mult);
  prep_pack11<<<512, 256, 0, stream>>>(w_hh_f, w_hh_b, mult, wpk);
  inproj_mfma3<<<dim3(16, 128), 256, 0, stream>>>(gemb, wih16, bias, xgf, xgb);
  lstm13<<<8, 1024, 0, stream>>>(wpk, mult, xgf, xgb, hbf);
  outproj2<<<1024, 256, 0, stream>>>(hbf, w_out, b_out, em);
  crf<<<64, 64, 0, stream>>>(tags, em, start_t, end_t, trans, part);
  finalize<<<1, 64, 0, stream>>>(part, (float*)d_out);
}

// Round 17
// 493.152 us; speedup vs baseline: 2.4120x; 2.4120x over previous
//
#include <hip/hip_runtime.h>
#include <hip/hip_bf16.h>
#include <stdint.h>

#define S_LEN 256
#define BATCH 64
#define HD 256
#define NT 9
#define NTOK (S_LEN*BATCH)   // 16384

typedef _Float16 hf2 __attribute__((ext_vector_type(2)));
typedef short bf16x8 __attribute__((ext_vector_type(8)));
typedef float f32x4 __attribute__((ext_vector_type(4)));

__device__ __forceinline__ float sigf(float x){ return 1.f/(1.f+__expf(-x)); }
__device__ __forceinline__ float tanh_(float x){ return 1.f - 2.f/(__expf(2.f*x)+1.f); }
__device__ __forceinline__ float wredsum(float v){
#pragma unroll
  for (int s = 32; s > 0; s >>= 1) v += __shfl_xor(v, s);
  return v;
}
__device__ __forceinline__ uint16_t f2b(float f){
  __hip_bfloat16 h = __float2bfloat16(f);
  return *(uint16_t*)&h;
}
__device__ __forceinline__ float b2f(uint16_t u){
  union{uint32_t i; float f;} a; a.i = ((uint32_t)u)<<16; return a.f;
}

__device__ __forceinline__ int sdot4(uint32_t a, uint32_t b, int c){
#if __has_builtin(__builtin_amdgcn_sdot4)
  return __builtin_amdgcn_sdot4((int)a, (int)b, c, false);
#else
  int r = c;
#pragma unroll
  for (int e = 0; e < 4; ++e) {
    int av = (int)(signed char)((a >> (8*e)) & 0xff);
    int bv = (int)(signed char)((b >> (8*e)) & 0xff);
    r += av * bv;
  }
  return r;
#endif
}

// quad reduce via DPP quad_perm (pure VALU)
__device__ __forceinline__ int qadd_xor1(int v){
#if __has_builtin(__builtin_amdgcn_update_dpp)
  return v + __builtin_amdgcn_update_dpp(0, v, 0xB1, 0xF, 0xF, false); // [1,0,3,2]
#else
  return v + __shfl_xor(v, 1);
#endif
}
__device__ __forceinline__ int qadd_xor2(int v){
#if __has_builtin(__builtin_amdgcn_update_dpp)
  return v + __builtin_amdgcn_update_dpp(0, v, 0x4E, 0xF, 0xF, false); // [2,3,0,1]
#else
  return v + __shfl_xor(v, 2);
#endif
}

// ---- merged prep: wih16/bias + gathered bf16 emb + per-column amax scale ----
__global__ __launch_bounds__(256) void prep_all(const int* __restrict__ inp,
    const float* __restrict__ emb,
    const float* __restrict__ wihf, const float* __restrict__ wihb,
    const float* __restrict__ bif, const float* __restrict__ bhf,
    const float* __restrict__ bib, const float* __restrict__ bhb,
    const float* __restrict__ whf, const float* __restrict__ whb,
    uint16_t* __restrict__ wih16, float* __restrict__ bias,
    uint16_t* __restrict__ gemb, float* __restrict__ mult){
  int blk = blockIdx.x, t = threadIdx.x;
  int idx = blk*256 + t;        // < 524288
  {
    int n = idx >> 8, k = idx & 255;
    const float* w = (n < 1024) ? wihf : wihb;
    wih16[idx] = f2b(w[(n & 1023)*256 + k]);
    if (idx < 2048)
      bias[idx] = (idx < 1024) ? (bif[idx] + bhf[idx]) : (bib[idx-1024] + bhb[idx-1024]);
  }
  {
    int m = idx >> 5;
    int k8 = (idx & 31)*8;
    int tok = inp[(m & 63)*S_LEN + (m >> 6)];
    const float* src = emb + (size_t)tok*256 + k8;
    float4 v0 = *(const float4*)(src);
    float4 v1 = *(const float4*)(src+4);
    uint16_t t16[8];
    t16[0]=f2b(v0.x); t16[1]=f2b(v0.y); t16[2]=f2b(v0.z); t16[3]=f2b(v0.w);
    t16[4]=f2b(v1.x); t16[5]=f2b(v1.y); t16[6]=f2b(v1.z); t16[7]=f2b(v1.w);
    *(uint4*)&gemb[(size_t)m*256 + k8] = *(uint4*)t16;
  }
  if (t < 64) {
    int dir = blk >> 10, col = blk & 1023;
    const float* w = (dir ? whb : whf) + (size_t)col*256 + t*4;
    float4 v = *(const float4*)w;
    float amax = fmaxf(fmaxf(fabsf(v.x), fabsf(v.y)), fmaxf(fabsf(v.z), fabsf(v.w)));
#pragma unroll
    for (int s = 32; s > 0; s >>= 1) amax = fmaxf(amax, __shfl_xor(amax, s));
    if (t == 0) mult[blk] = amax / 16129.f;
  }
}

// ---- prep: pack w_hh to i8x4 for lstm10's (j, ks) layout ----
// tid = j*4+ks. Thread owns unit j, 4 gates, k-window [64ks, +64) = 16 dwords/gate.
__global__ void prep_pack9(const float* __restrict__ whf, const float* __restrict__ whb,
                           const float* __restrict__ mult, uint32_t* __restrict__ wpk9){
  int idx = blockIdx.x*256 + threadIdx.x;   // < 131072
  int dir = idx >> 16;
  int rem = idx & 65535;
  int r = rem >> 10;        // 0..63 = g*16 + p
  int tid = rem & 1023;
  int g = r >> 4, p = r & 15;
  int j = tid >> 2, ks = tid & 3;
  int col = g*256 + j;
  const float* w = (dir ? whb : whf) + (size_t)col*256 + ks*64 + p*4;
  float sw = mult[dir*1024 + col] * 127.f;
  float inv = (sw > 0.f) ? (1.f/sw) : 0.f;
  uint32_t pk = 0;
#pragma unroll
  for (int e = 0; e < 4; ++e) {
    float q = rintf(w[e] * inv);
    q = fminf(127.f, fmaxf(-127.f, q));
    int qi = (int)q;
    pk |= ((uint32_t)(qi & 0xff)) << (8*e);
  }
  wpk9[idx] = pk;
}

// ---- input projection via MFMA, 128x128 tile; XCD-chunk swizzle ----
__global__ __launch_bounds__(256, 2) void inproj_mfma3(const uint16_t* __restrict__ gemb,
    const uint16_t* __restrict__ wih16, const float* __restrict__ bias,
    uint16_t* __restrict__ xgf, uint16_t* __restrict__ xgb){
  __shared__ uint16_t As[128][72];   // A[m][k] bf16, +8 pad
  __shared__ uint16_t Bs[128][72];   // B^T[c][k] bf16, +8 pad
  int flat = blockIdx.x + blockIdx.y*16;   // 2048 blocks
  int nf = (flat & 7)*256 + (flat >> 3);   // XCD x owns contiguous range
  int bn = nf & 15, bm = nf >> 4;
  int tid = threadIdx.x;
  int w = tid >> 6, l = tid & 63;
  int lr = l & 15, lg = l >> 4;
  f32x4 acc[2][8];
#pragma unroll
  for (int am = 0; am < 2; ++am)
#pragma unroll
    for (int cf = 0; cf < 8; ++cf) acc[am][cf] = (f32x4){0.f,0.f,0.f,0.f};

  int sr = tid >> 1, sh = tid & 1;   // staging: row sr, 32-half chunk sh

  for (int k0 = 0; k0 < 256; k0 += 64) {
    {
      const uint16_t* asrc = gemb + (size_t)(bm*128 + sr)*256 + k0 + sh*32;
      uint4 a0 = *(const uint4*)(asrc+0);
      uint4 a1 = *(const uint4*)(asrc+8);
      uint4 a2 = *(const uint4*)(asrc+16);
      uint4 a3 = *(const uint4*)(asrc+24);
      *(uint4*)&As[sr][sh*32+0]  = a0;
      *(uint4*)&As[sr][sh*32+8]  = a1;
      *(uint4*)&As[sr][sh*32+16] = a2;
      *(uint4*)&As[sr][sh*32+24] = a3;
    }
    {
      const uint16_t* bsrc = wih16 + (size_t)(bn*128 + sr)*256 + k0 + sh*32;
      uint4 b0 = *(const uint4*)(bsrc+0);
      uint4 b1 = *(const uint4*)(bsrc+8);
      uint4 b2 = *(const uint4*)(bsrc+16);
      uint4 b3 = *(const uint4*)(bsrc+24);
      *(uint4*)&Bs[sr][sh*32+0]  = b0;
      *(uint4*)&Bs[sr][sh*32+8]  = b1;
      *(uint4*)&Bs[sr][sh*32+16] = b2;
      *(uint4*)&Bs[sr][sh*32+24] = b3;
    }
    __syncthreads();
#pragma unroll
    for (int ks = 0; ks < 2; ++ks) {
      int koff = ks*32 + lg*8;
      bf16x8 a0 = *(const bf16x8*)&As[32*w + lr][koff];
      bf16x8 a1 = *(const bf16x8*)&As[32*w + 16 + lr][koff];
#pragma unroll
      for (int cf = 0; cf < 8; ++cf) {
        bf16x8 b = *(const bf16x8*)&Bs[cf*16 + lr][koff];
        acc[0][cf] = __builtin_amdgcn_mfma_f32_16x16x32_bf16(a0, b, acc[0][cf], 0, 0, 0);
        acc[1][cf] = __builtin_amdgcn_mfma_f32_16x16x32_bf16(a1, b, acc[1][cf], 0, 0, 0);
      }
    }
    __syncthreads();
  }
  int n0 = bn*128;
  bool back = (n0 >= 1024);
  uint16_t* dst = back ? xgb : xgf;
  int nb0 = back ? (n0 - 1024) : n0;
#pragma unroll
  for (int cf = 0; cf < 8; ++cf) {
    int nc = cf*16 + lr;
    int nd = nb0 + nc;                 // within-dir column
    int gj = (nd & 255)*4 + (nd >> 8); // unit-major, gate-minor position
    float bv = bias[n0 + nc];
#pragma unroll
    for (int am = 0; am < 2; ++am)
#pragma unroll
    for (int r = 0; r < 4; ++r) {
      int m = bm*128 + 32*w + am*16 + lg*4 + r;
      dst[(size_t)m*1024 + gj] = f2b(acc[am][cf][r] + bv);
    }
  }
}

// ---- recurrence: one wg per (dir, batch); 1024 threads = (unit j, k-quarter ks) ----
// i8 dot4, weights reg-resident; quad reduce via DPP (VALU pipe); raw s_barrier
// with lgkmcnt-only drain. Best-known config (R12/R14: 379 us).
__global__ __launch_bounds__(1024, 4)
void lstm10(const uint32_t* __restrict__ wpk9, const float* __restrict__ mult,
    const uint16_t* __restrict__ xgf, const uint16_t* __restrict__ xgb,
    __hip_bfloat16* __restrict__ hout){
  int dir = blockIdx.x >> 6;
  int b = blockIdx.x & 63;
  int tid = threadIdx.x;
  int j = tid >> 2, ks = tid & 3;
  __shared__ __align__(16) uint32_t hs8[2][64];   // h as i8*127, double-buffered

  const uint32_t* wp = wpk9 + (size_t)dir*65536 + tid;
  uint32_t wreg[64];
#pragma unroll
  for (int r = 0; r < 64; ++r) wreg[r] = wp[r*1024];
#pragma unroll
  for (int r = 0; r < 64; ++r) asm volatile("" : "+v"(wreg[r]));
  asm volatile("" ::: "memory");

  float m4[4];
#pragma unroll
  for (int g = 0; g < 4; ++g) m4[g] = mult[dir*1024 + g*256 + j];

  if (tid < 128) hs8[tid >> 6][tid & 63] = 0u;
  float cst = 0.f;
  const uint16_t* xgp = (dir ? xgb : xgf) + (size_t)b*1024 + j*4;
  __syncthreads();

  int ts0 = dir ? (S_LEN-1) : 0;
  int ts1 = dir ? (S_LEN-2) : 1;
  uint2 xA = *(const uint2*)(xgp + (size_t)ts0*65536);   // depth-2 prefetch
  uint2 xB = *(const uint2*)(xgp + (size_t)ts1*65536);
  for (int t = 0; t < S_LEN; ++t) {
    int ts = dir ? (S_LEN-1-t) : t;
    int cur = t & 1;
    uint2 xC = xB;
    if (t + 2 < S_LEN) {
      int tn = dir ? (S_LEN-3-t) : (t+2);
      xC = *(const uint2*)(xgp + (size_t)tn*65536);
    }
    // h window: 16 dwords (64 i8) at dword ks*16
    const uint4* hp = (const uint4*)&hs8[cur][ks*16];
    uint4 h0 = hp[0], h1 = hp[1], h2 = hp[2], h3 = hp[3];
    int zi[4] = {0,0,0,0};
#pragma unroll
    for (int g = 0; g < 4; ++g) {
      const uint32_t* wg_ = &wreg[g*16];
      zi[g] = sdot4(wg_[0],  h0.x, zi[g]);
      zi[g] = sdot4(wg_[1],  h0.y, zi[g]);
      zi[g] = sdot4(wg_[2],  h0.z, zi[g]);
      zi[g] = sdot4(wg_[3],  h0.w, zi[g]);
      zi[g] = sdot4(wg_[4],  h1.x, zi[g]);
      zi[g] = sdot4(wg_[5],  h1.y, zi[g]);
      zi[g] = sdot4(wg_[6],  h1.z, zi[g]);
      zi[g] = sdot4(wg_[7],  h1.w, zi[g]);
      zi[g] = sdot4(wg_[8],  h2.x, zi[g]);
      zi[g] = sdot4(wg_[9],  h2.y, zi[g]);
      zi[g] = sdot4(wg_[10], h2.z, zi[g]);
      zi[g] = sdot4(wg_[11], h2.w, zi[g]);
      zi[g] = sdot4(wg_[12], h3.x, zi[g]);
      zi[g] = sdot4(wg_[13], h3.y, zi[g]);
      zi[g] = sdot4(wg_[14], h3.z, zi[g]);
      zi[g] = sdot4(wg_[15], h3.w, zi[g]);
    }
    // exact i32 quad reduce on the VALU pipe (DPP quad_perm)
#pragma unroll
    for (int g = 0; g < 4; ++g) zi[g] = qadd_xor1(zi[g]);
#pragma unroll
    for (int g = 0; g < 4; ++g) zi[g] = qadd_xor2(zi[g]);
    float zf[4];
    zf[0] = (float)zi[0]*m4[0] + b2f((uint16_t)(xA.x & 0xffff));
    zf[1] = (float)zi[1]*m4[1] + b2f((uint16_t)(xA.x >> 16));
    zf[2] = (float)zi[2]*m4[2] + b2f((uint16_t)(xA.y & 0xffff));
    zf[3] = (float)zi[3]*m4[3] + b2f((uint16_t)(xA.y >> 16));
    float ig = sigf(zf[0]), fg = sigf(zf[1]), gg = tanh_(zf[2]), og = sigf(zf[3]);
    cst = fg*cst + ig*gg;
    float hj = og * tanh_(cst);
    if (ks == 0) {
      int q = (int)rintf(hj * 127.f);
      ((unsigned char*)&hs8[cur^1][0])[j] = (unsigned char)(q & 0xff);
      hout[((size_t)ts*BATCH + b)*512 + dir*256 + j] = __float2bfloat16(hj);
    }
    // raw barrier: drain LDS only; global loads/stores stay in flight
    __builtin_amdgcn_sched_barrier(0);
    asm volatile("s_waitcnt lgkmcnt(0)" ::: "memory");
    __builtin_amdgcn_sched_barrier(0);
    __builtin_amdgcn_s_barrier();
    __builtin_amdgcn_sched_barrier(0);
    xA = xB; xB = xC;
  }
}

// ---- output projection: 1024 blocks x 16 tokens (amortize w_out staging) ----
__global__ __launch_bounds__(256) void outproj2(const __hip_bfloat16* __restrict__ hb,
    const float* __restrict__ w_out, const float* __restrict__ b_out,
    float* __restrict__ em){
  __shared__ float wsm[NT*512];
  __shared__ float bsm[NT];
  int tid = threadIdx.x;
  for (int i = tid; i < NT*512; i += 256) wsm[i] = w_out[512 + i];  // rows 1..9
  if (tid < NT) bsm[tid] = b_out[1 + tid];
  __syncthreads();
  int wave = tid >> 6, l = tid & 63;
#pragma unroll
  for (int it = 0; it < 4; ++it) {
    int m = blockIdx.x*16 + it*4 + wave;
    const __hip_bfloat16* hp = hb + (size_t)m*512;
    float hv[8];
#pragma unroll
    for (int q = 0; q < 8; ++q) hv[q] = __bfloat162float(hp[l + 64*q]);
    for (int jj = 0; jj < NT; ++jj) {
      float p = 0.f;
#pragma unroll
      for (int q = 0; q < 8; ++q) p += hv[q]*wsm[jj*512 + 64*q + l];
      p = wredsum(p);
      if (l == 0) em[(size_t)m*NT + jj] = p + bsm[jj];
    }
  }
}

// ---- CRF: one wave per batch item; lanes 0..8 hold the 9-state score ----
__global__ __launch_bounds__(64) void crf(const int* __restrict__ tags,
    const float* __restrict__ em, const float* __restrict__ start_t,
    const float* __restrict__ end_t, const float* __restrict__ trans,
    float* __restrict__ part){
  int b = blockIdx.x;
  int l = threadIdx.x;
  float np = 0.f;
  for (int t = l; t < S_LEN; t += 64) {
    int tg = tags[b*S_LEN + t] - 1;
    float e = em[(size_t)(t*BATCH + b)*NT + tg];
    float tr = (t == 0) ? start_t[tg] : trans[(tags[b*S_LEN + t - 1] - 1)*NT + tg];
    np += e + tr;
  }
  float num = wredsum(np);
  num += end_t[tags[b*S_LEN + S_LEN-1] - 1];
  int j = (l < NT) ? l : 0;
  float tj[NT];
#pragma unroll
  for (int i = 0; i < NT; ++i) tj[i] = trans[i*NT + j];
  float sc = start_t[j] + em[(size_t)b*NT + j];
  for (int t = 1; t < S_LEN; ++t) {
    float e = em[(size_t)(t*BATCH + b)*NT + j];
    float m = -1e30f;
    float vals[NT];
#pragma unroll
    for (int i = 0; i < NT; ++i) { float si = __shfl(sc, i); vals[i] = si + tj[i]; m = fmaxf(m, vals[i]); }
    float ssum = 0.f;
#pragma unroll
    for (int i = 0; i < NT; ++i) ssum += __expf(vals[i] - m);
    sc = e + m + __logf(ssum);
  }
  float vj = (l < NT) ? (sc + end_t[l]) : -1e30f;
  float mx = vj;
#pragma unroll
  for (int s2 = 32; s2 > 0; s2 >>= 1) mx = fmaxf(mx, __shfl_xor(mx, s2));
  float es = __expf(vj - mx);
  es = wredsum(es);
  if (l == 0) part[b] = num - (mx + __logf(es));
}

__global__ void finalize(const float* __restrict__ part, float* __restrict__ out){
  float v = part[threadIdx.x];
  v = wredsum(v);
  if (threadIdx.x == 0) out[0] = -(v / 64.f);
}

extern "C" void kernel_launch(void* const* d_in, const int* in_sizes, int n_in,
                              void* d_out, int out_size, void* d_ws, size_t ws_size,
                              hipStream_t stream) {
  (void)in_sizes; (void)n_in; (void)out_size; (void)ws_size;
  const int*   inputs  = (const int*)d_in[0];
  const int*   tags    = (const int*)d_in[1];
  const float* emb     = (const float*)d_in[3];
  const float* w_ih_f  = (const float*)d_in[4];
  const float* w_hh_f  = (const float*)d_in[5];
  const float* b_ih_f  = (const float*)d_in[6];
  const float* b_hh_f  = (const float*)d_in[7];
  const float* w_ih_b  = (const float*)d_in[8];
  const float* w_hh_b  = (const float*)d_in[9];
  const float* b_ih_b  = (const float*)d_in[10];
  const float* b_hh_b  = (const float*)d_in[11];
  const float* w_out   = (const float*)d_in[12];
  const float* b_out   = (const float*)d_in[13];
  const float* start_t = (const float*)d_in[14];
  const float* end_t   = (const float*)d_in[15];
  const float* trans   = (const float*)d_in[16];

  char* ws = (char*)d_ws;
  size_t off = 0;
  auto alloc = [&](size_t bytes) -> void* {
    void* p = ws + off;
    off = (off + bytes + 255) & ~(size_t)255;
    return p;
  };
  uint16_t* xgf = (uint16_t*)alloc((size_t)NTOK*1024*2);
  uint16_t* xgb = (uint16_t*)alloc((size_t)NTOK*1024*2);
  __hip_bfloat16* hbf = (__hip_bfloat16*)alloc((size_t)NTOK*512*2);
  float*    em    = (float*)alloc((size_t)NTOK*NT*4);
  uint16_t* wih16 = (uint16_t*)alloc((size_t)2048*256*2);
  uint16_t* gemb  = (uint16_t*)alloc((size_t)NTOK*256*2);
  float*    bias  = (float*)alloc((size_t)2048*4);
  float*    mult  = (float*)alloc((size_t)2048*4);
  uint32_t* wpk9  = (uint32_t*)alloc((size_t)2*64*1024*4);
  float*    part  = (float*)alloc((size_t)64*4);

  prep_all<<<2048, 256, 0, stream>>>(inputs, emb, w_ih_f, w_ih_b, b_ih_f, b_hh_f,
                                     b_ih_b, b_hh_b, w_hh_f, w_hh_b,
                                     wih16, bias, gemb, mult);
  prep_pack9<<<512, 256, 0, stream>>>(w_hh_f, w_hh_b, mult, wpk9);
  inproj_mfma3<<<dim3(16, 128), 256, 0, stream>>>(gemb, wih16, bias, xgf, xgb);
  lstm10<<<128, 1024, 0, stream>>>(wpk9, mult, xgf, xgb, hbf);
  outproj2<<<1024, 256, 0, stream>>>(hbf, w_out, b_out, em);
  crf<<<64, 64, 0, stream>>>(tags, em, start_t, end_t, trans, part);
  finalize<<<1, 64, 0, stream>>>(part, (float*)d_out);
}